// Round 1
// 208.215 us; speedup vs baseline: 1.0244x; 1.0244x over previous
//
#include <hip/hip_runtime.h>

typedef __bf16 bf16x8 __attribute__((ext_vector_type(8)));
typedef unsigned short us8 __attribute__((ext_vector_type(8)));
typedef unsigned short us2 __attribute__((ext_vector_type(2)));
typedef float f32x16 __attribute__((ext_vector_type(16)));

#define N_IMG 32
#define CI 16
#define HH 256
#define WW 256
#define CO 64
#define OHH 254
#define OWW 254

#define XS_W 258              // 256 + 2 zero-pad columns
#define SC 16                 // shorts per (row,w) cell: 32B, dense => conflict-free
#define NSTRIP 24             // 32*24 = 768 blocks = exactly 3 resident/CU
#define WP_SHORTS (CO * 160)
#define WS_NEEDED ((size_t)WP_SHORTS * 2)

__device__ __forceinline__ unsigned short f2bf(float f) {
  union { float f; unsigned u; } v; v.f = f;
  return (unsigned short)((v.u + 0x7FFFu + ((v.u >> 16) & 1u)) >> 16);  // RNE
}

#if defined(__has_builtin)
#if __has_builtin(__builtin_amdgcn_cvt_pk_bf16_f32)
#define HAVE_CVT_PK 1
#endif
#endif

__device__ __forceinline__ us2 cvt2(float a, float b) {
#ifdef HAVE_CVT_PK
  typedef __bf16 bf16x2 __attribute__((ext_vector_type(2)));
  bf16x2 r = __builtin_amdgcn_cvt_pk_bf16_f32(a, b);  // lo=a, hi=b, RNE
  return __builtin_bit_cast(us2, r);
#else
  us2 r; r[0] = f2bf(a); r[1] = f2bf(b); return r;
#endif
}

__device__ __forceinline__ float fast_tanh(float x) {
  float cx = fminf(fmaxf(x, -15.f), 15.f);
  float e = __expf(2.f * cx);
  return (e - 1.f) / (e + 1.f);
}

// ---- prep: weights+bias -> bf16 A-side layout wp[oc][tap*16+ci] (20 KB) ----
__global__ void prep_w(const float* __restrict__ wg, const float* __restrict__ bg,
                       unsigned short* __restrict__ wp) {
  int idx = blockIdx.x * 256 + threadIdx.x;
  if (idx >= WP_SHORTS) return;
  int oc = idx / 160;
  int k = idx - oc * 160;
  int tap = k >> 4, ci = k & 15;
  float v;
  if (tap < 9)      v = wg[oc * 144 + ci * 9 + tap];
  else if (ci == 0) v = bg[oc];
  else              v = 0.f;
  wp[idx] = f2bf(v);
}

// ---- fused conv+min+tanh: rolling-window strip kernel ----
// One block owns ~11 consecutive output rows of one image. LDS holds a 4-row
// ring (slot = input_row & 3) of bf16 x in [row][w][ci] cells (32B, dense).
// Per iteration: issue 16 global loads for input row oh+3 (hidden under the
// MFMA work of output row oh), compute row oh from ring slots oh..oh+2,
// convert+ds_write the staged row, store, one barrier. Halo amplification
// (254+2*NSTRIP)/254 = 1.19x vs the old 2x; staging overlaps compute.
// Ring race-freedom: iter oh reads rows oh..oh+2 (slots oh&3..(oh+2)&3),
// writes slot (oh+3)&3 == (oh-1)&3 whose last readers finished in iter oh-1
// (barrier-separated). Numerics identical to previous kernel (same cvt,
// same MFMA order, same fmin tree).
__global__ __launch_bounds__(256, 3)
void conv_fused(const float* __restrict__ xg, const unsigned short* __restrict__ wp,
                float* __restrict__ out) {
  __shared__ __align__(16) unsigned short xs[4 * XS_W * SC];  // 33 KB
  const int t = threadIdx.x;
  const int n = blockIdx.x / NSTRIP;
  const int s = blockIdx.x - n * NSTRIP;
  // 254 rows over 24 strips: 14 strips of 11 rows, 10 strips of 10 rows
  const int oh0 = s * 10 + (s < 14 ? s : 14);
  const int nrows = (s < 14) ? 11 : 10;
  const int oh1 = oh0 + nrows;

  const float* srcT = xg + (size_t)n * (CI * HH * WW) + t;

  // ---- prologue: stage input rows oh0..oh0+2 into their ring slots ----
  {
    float v[3][16];
#pragma unroll
    for (int r = 0; r < 3; ++r)
#pragma unroll
      for (int j = 0; j < 16; ++j)
        v[r][j] = srcT[((size_t)j * HH + (oh0 + r)) * WW];
#pragma unroll
    for (int r = 0; r < 3; ++r) {
      union { us8 v8[2]; us2 v2[8]; } pk;
#pragma unroll
      for (int j = 0; j < 8; ++j) pk.v2[j] = cvt2(v[r][2 * j], v[r][2 * j + 1]);
      const int slot = (oh0 + r) & 3;
      *(us8*)(xs + (slot * XS_W + t) * SC) = pk.v8[0];      // ds_write_b128
      *(us8*)(xs + (slot * XS_W + t) * SC + 8) = pk.v8[1];  // ds_write_b128
    }
  }
  if (t < 128) {  // zero pad columns w=256,257 for all 4 ring slots (persist)
    const int slot = t >> 5, rem = t & 31;
    xs[(slot * XS_W + 256 + (rem >> 4)) * SC + (rem & 15)] = 0;
  }

  const int lane = t & 63, wave = t >> 6;
  const int lr = lane & 31, qh = lane >> 5;

  // preload A-frags ONCE (2 mt x 10 taps x 4 VGPR = 80 VGPRs), wp is L2-hot
  const unsigned short* wpl = wp + lr * 160 + qh * 8;
  bf16x8 afrag[2][10];
#pragma unroll
  for (int mt = 0; mt < 2; ++mt)
#pragma unroll
    for (int tap = 0; tap < 10; ++tap)
      afrag[mt][tap] =
          __builtin_bit_cast(bf16x8, *(const us8*)(wpl + mt * 32 * 160 + tap * 16));

  us8 onev = {};
  if (qh == 0) onev[0] = 0x3F80;
  const bf16x8 xone = __builtin_bit_cast(bf16x8, onev);

  const int pb = wave * 64;  // this wave's 64-pixel strip

  __syncthreads();

  for (int oh = oh0; oh < oh1; ++oh) {
    const bool do_stage = (oh + 1 < oh1);  // last iter stages nothing

    // issue next-row global loads FIRST; they drain under the MFMA below
    float v[16];
    if (do_stage) {
#pragma unroll
      for (int j = 0; j < 16; ++j)
        v[j] = srcT[((size_t)j * HH + (oh + 3)) * WW];
    }

    float vmin[2];
#pragma unroll
    for (int nt = 0; nt < 2; ++nt) {  // sequential nt: acc = 32 VGPR not 64
      f32x16 acc0, acc1;
#pragma unroll
      for (int e = 0; e < 16; ++e) { acc0[e] = 0.f; acc1[e] = 0.f; }
#pragma unroll
      for (int tap = 0; tap < 9; ++tap) {
        const int kh = tap / 3, kw = tap - kh * 3;
        const int slot = (oh + kh) & 3;
        bf16x8 xf = __builtin_bit_cast(
            bf16x8,
            *(const us8*)(xs + (slot * XS_W + pb + nt * 32 + lr + kw) * SC + qh * 8));
        acc0 = __builtin_amdgcn_mfma_f32_32x32x16_bf16(afrag[0][tap], xf, acc0, 0, 0, 0);
        acc1 = __builtin_amdgcn_mfma_f32_32x32x16_bf16(afrag[1][tap], xf, acc1, 0, 0, 0);
      }
      // bias tap: B = e_{k=144}
      acc0 = __builtin_amdgcn_mfma_f32_32x32x16_bf16(afrag[0][9], xone, acc0, 0, 0, 0);
      acc1 = __builtin_amdgcn_mfma_f32_32x32x16_bf16(afrag[1][9], xone, acc1, 0, 0, 0);

      float mv = acc0[0];
#pragma unroll
      for (int e = 1; e < 16; ++e) mv = fminf(mv, acc0[e]);
#pragma unroll
      for (int e = 0; e < 16; ++e) mv = fminf(mv, acc1[e]);
      mv = fminf(mv, __shfl_xor(mv, 32, 64));
      vmin[nt] = fast_tanh(fast_tanh(mv));
    }

    // convert + write the staged row into its ring slot (disjoint from reads)
    if (do_stage) {
      union { us8 v8[2]; us2 v2[8]; } pk;
#pragma unroll
      for (int j = 0; j < 8; ++j) pk.v2[j] = cvt2(v[2 * j], v[2 * j + 1]);
      const int slot = (oh + 3) & 3;
      *(us8*)(xs + (slot * XS_W + t) * SC) = pk.v8[0];
      *(us8*)(xs + (slot * XS_W + t) * SC + 8) = pk.v8[1];
    }

    const float res = (lane < 32) ? vmin[0] : vmin[1];
    const int ow = pb + lane;
    if (ow < OWW) out[((size_t)n * OHH + oh) * OWW + ow] = res;

    __syncthreads();
  }
}

// ================= fallback (round-1 kernel) if ws too small ================
#define XS_C 24
#define WS_K 168
__global__ __launch_bounds__(256, 2)
void conv_min_tanh(const float* __restrict__ xg, const float* __restrict__ wg,
                   const float* __restrict__ bg, float* __restrict__ out) {
  __shared__ __align__(16) unsigned short xs[3 * XS_W * XS_C];
  __shared__ __align__(16) unsigned short ws[CO * WS_K];
  const int t = threadIdx.x;
  const int n = blockIdx.x / OHH;
  const int oh = blockIdx.x % OHH;
#pragma unroll
  for (int i = 0; i < 36; ++i) {
    int f = i * 256 + t;
    int oc = f / 144;
    int r = f - oc * 144;
    int ci = r / 9;
    int tap = r - ci * 9;
    ws[oc * WS_K + tap * 16 + ci] = f2bf(wg[f]);
  }
  if (t < CO) ws[t * WS_K + 144] = f2bf(bg[t]);
  for (int i = t; i < CO * 15; i += 256) {
    int oc = i / 15;
    ws[oc * WS_K + 145 + (i - oc * 15)] = 0;
  }
  {
    const size_t base_n = (size_t)n * CI * HH * WW;
#pragma unroll
    for (int kh = 0; kh < 3; ++kh) {
#pragma unroll
      for (int half = 0; half < 2; ++half) {
        float v[8];
#pragma unroll
        for (int j = 0; j < 8; ++j) {
          int ci = half * 8 + j;
          v[j] = xg[base_n + ((size_t)ci * HH + (oh + kh)) * WW + t];
        }
        us8 pk;
#pragma unroll
        for (int j = 0; j < 8; ++j) pk[j] = f2bf(v[j]);
        *(us8*)(xs + (kh * XS_W + t) * XS_C + half * 8) = pk;
      }
    }
  }
  if (t < 96) {
    int kh = t >> 5;
    int rem = t & 31;
    int w = 256 + (rem >> 4);
    int ci = rem & 15;
    xs[(kh * XS_W + w) * XS_C + ci] = 0;
  }
  __syncthreads();
  const int lane = t & 63, wave = t >> 6;
  const int lr = lane & 31, qh = lane >> 5;
  bf16x8 afrag[2][10];
#pragma unroll
  for (int mt = 0; mt < 2; ++mt) {
    const unsigned short* wq = ws + (mt * 32 + lr) * WS_K + qh * 8;
#pragma unroll
    for (int tap = 0; tap < 10; ++tap)
      afrag[mt][tap] = __builtin_bit_cast(bf16x8, *(const us8*)(wq + tap * 16));
  }
  f32x16 acc[2][2];
#pragma unroll
  for (int a = 0; a < 2; ++a)
#pragma unroll
    for (int b = 0; b < 2; ++b)
#pragma unroll
      for (int e = 0; e < 16; ++e) acc[a][b][e] = 0.f;
  const unsigned short* xq = xs + (wave * 64 + lr) * XS_C + qh * 8;
#pragma unroll
  for (int tap = 0; tap < 9; ++tap) {
    const int kh = tap / 3, kw = tap - kh * 3;
#pragma unroll
    for (int nt = 0; nt < 2; ++nt) {
      bf16x8 xf = __builtin_bit_cast(
          bf16x8, *(const us8*)(xq + (kh * XS_W + nt * 32 + kw) * XS_C));
      acc[0][nt] = __builtin_amdgcn_mfma_f32_32x32x16_bf16(afrag[0][tap], xf,
                                                           acc[0][nt], 0, 0, 0);
      acc[1][nt] = __builtin_amdgcn_mfma_f32_32x32x16_bf16(afrag[1][tap], xf,
                                                           acc[1][nt], 0, 0, 0);
    }
  }
  {
    us8 one = {};
    if (qh == 0) one[0] = 0x3F80;
    bf16x8 xone = __builtin_bit_cast(bf16x8, one);
#pragma unroll
    for (int nt = 0; nt < 2; ++nt) {
      acc[0][nt] = __builtin_amdgcn_mfma_f32_32x32x16_bf16(afrag[0][9], xone,
                                                           acc[0][nt], 0, 0, 0);
      acc[1][nt] = __builtin_amdgcn_mfma_f32_32x32x16_bf16(afrag[1][9], xone,
                                                           acc[1][nt], 0, 0, 0);
    }
  }
  float vmin[2];
#pragma unroll
  for (int nt = 0; nt < 2; ++nt) {
    float v = acc[0][nt][0];
#pragma unroll
    for (int e = 1; e < 16; ++e) v = fminf(v, acc[0][nt][e]);
#pragma unroll
    for (int e = 0; e < 16; ++e) v = fminf(v, acc[1][nt][e]);
    v = fminf(v, __shfl_xor(v, 32, 64));
    vmin[nt] = fast_tanh(fast_tanh(v));
  }
  float res = (lane < 32) ? vmin[0] : vmin[1];
  int ow = wave * 64 + lane;
  if (ow < OWW) out[((size_t)n * OHH + oh) * OWW + ow] = res;
}

extern "C" void kernel_launch(void* const* d_in, const int* in_sizes, int n_in,
                              void* d_out, int out_size, void* d_ws, size_t ws_size,
                              hipStream_t stream) {
  const float* x = (const float*)d_in[0];
  const float* w = (const float*)d_in[1];
  const float* b = (const float*)d_in[2];
  float* out = (float*)d_out;
  if (ws_size >= WS_NEEDED) {
    unsigned short* wp = (unsigned short*)d_ws;
    prep_w<<<dim3((WP_SHORTS + 255) / 256), dim3(256), 0, stream>>>(w, b, wp);
    conv_fused<<<dim3(N_IMG * NSTRIP), dim3(256), 0, stream>>>(x, wp, out);
  } else {
    conv_min_tanh<<<dim3(N_IMG * OHH), dim3(256), 0, stream>>>(x, w, b, out);
  }
}